// Round 12
// baseline (356.498 us; speedup 1.0000x reference)
//
#include <hip/hip_runtime.h>
#include <hip/hip_cooperative_groups.h>

namespace cg = cooperative_groups;

// IBNModel fused: prep -> msg -> rec in ONE cooperative kernel (grid-wide
// syncs between phases). 512 blocks x 512 thr, 64 KB LDS -> 2 blocks/CU
// co-resident (= max coop capacity). Fallback: 3 separate launches of the
// same phases if cooperative launch is rejected (e.g. under graph capture).

typedef _Float16 half8_t __attribute__((ext_vector_type(8)));
typedef __fp16 fp16x2_t __attribute__((ext_vector_type(2)));
typedef float float4_t __attribute__((ext_vector_type(4)));

#define PIN(x) asm volatile("" : "+v"(x))

__device__ __forceinline__ float exp2_(float x) { return __builtin_amdgcn_exp2f(x); }
__device__ __forceinline__ float rcp_(float x) { return __builtin_amdgcn_rcpf(x); }

struct P {
  const float *E1f, *E2f, *E1b, *E2b, *adj, *x, *Wf, *Uf, *bf, *Wb, *bb;
  const float *dec_w, *dec_b, *out_w, *out_b;
  float* out;
  _Float16 *adjT, *AfT, *AbT, *ufrag, *wbfrag, *zpad, *msg16, *msgb16;
};

// ---------------- phase 1: prep (512 blocks x 512 thr) ----------------------
// Every block: 2 softmax rows (transposed fp16 stores). Extra jobs by bid:
// 0-127 adjT (4 rows), 128-247 ufrag region, 248-263 wbfrag, 264 zpad.
__device__ void phase_prep(const P& p, char* smem, int bid, int tid) {
  float* red = (float*)smem;           // 512 floats
  float* e1s = (float*)(smem + 2048);  // 32 floats
  for (int rr = 0; rr < 2; ++rr) {
    int rowid = bid * 2 + rr;
    int which = rowid >> 9, row = rowid & 511;
    const float* E1 = which ? p.E1b : p.E1f;
    const float* E2 = which ? p.E2b : p.E2f;
    _Float16* A = which ? p.AbT : p.AfT;
    __syncthreads();
    if (tid < 32) e1s[tid] = E1[row * 32 + tid];
    __syncthreads();
    const float4* e2 = (const float4*)(E2 + tid * 32);
    float acc = 0.f;
#pragma unroll
    for (int d4 = 0; d4 < 8; ++d4) {
      float4 v = e2[d4];
      acc = fmaf(v.x, e1s[d4 * 4 + 0], acc);
      acc = fmaf(v.y, e1s[d4 * 4 + 1], acc);
      acc = fmaf(v.z, e1s[d4 * 4 + 2], acc);
      acc = fmaf(v.w, e1s[d4 * 4 + 3], acc);
    }
    float s = fmaxf(acc, 0.f);
    red[tid] = s;
    __syncthreads();
    for (int off = 256; off > 0; off >>= 1) {
      if (tid < off) red[tid] = fmaxf(red[tid], red[tid + off]);
      __syncthreads();
    }
    float mx = red[0];
    __syncthreads();
    float e0 = __expf(s - mx);
    red[tid] = e0;
    __syncthreads();
    for (int off = 256; off > 0; off >>= 1) {
      if (tid < off) red[tid] += red[tid + off];
      __syncthreads();
    }
    float inv = rcp_(red[0]);
    A[(size_t)tid * 512 + row] = (_Float16)(e0 * inv);  // transposed
  }
  if (bid < 128) {  // adjT
    int base = bid * 4;
    for (int r = 0; r < 4; ++r) {
      int row = base + r;
      p.adjT[(size_t)tid * 512 + row] = (_Float16)p.adj[row * 512 + tid];
    }
  } else if (bid < 248) {  // ufrag region r = (og*3+gi)*5+kb, pre-scaled
    int r = bid - 128;
    int kb = r % 5, gi = (r / 5) % 3, og = r / 15;
    float scl = (gi == 2) ? 2.8853902f : -1.4426950f;
    int lane = tid >> 3, j = tid & 7;
    int o = og * 16 + (lane & 15);
    int q4 = lane >> 4;
    float v;
    if (kb < 4) {
      v = p.Uf[gi * 16384 + o * 128 + kb * 32 + q4 * 8 + j];
    } else {
      int q = q4 * 8 + j;
      v = (q < 9) ? p.Wf[gi * 1152 + o * 9 + q]
                  : (q == 9 ? p.bf[gi * 128 + o] : 0.f);
    }
    p.ufrag[r * 512 + tid] = (_Float16)(v * scl);
  } else if (bid < 264) {  // wbfrag r2 = og*2 + (gi-1)
    int r2 = bid - 248;
    int gi = 1 + (r2 & 1), og = r2 >> 1;
    float scl = (gi == 2) ? 2.8853902f : -1.4426950f;
    int lane = tid >> 3, j = tid & 7;
    int o = og * 16 + (lane & 15);
    int q = (lane >> 4) * 8 + j;
    float v = (q < 9) ? p.Wb[gi * 1152 + o * 9 + q]
                      : (q == 9 ? p.bb[gi * 128 + o] : 0.f);
    p.wbfrag[r2 * 512 + tid] = (_Float16)(v * scl);
  } else if (bid == 264) {
    if (tid < 64) p.zpad[tid] = (_Float16)0.f;
  }
}

// ---------------- phase 2: msg GEMM (512 blocks x 512 thr) ------------------
// block = t(bid>>3) x two 32-col halves (nc = (bid&7), (bid&7)+8). 8 waves:
// og<6 MFMA (nt=og&1 n16-tile, mat=og>>1: 0=adj,1=Af,2=Ab), og>=6 fill waves.
// Output rows 16 halves: j0-2=x, j3-5=x@adj, j6-8=x@Af, j9=1, j10-15=0.
__device__ void phase_msg(const P& p, char* smem, int bid, int tid) {
  _Float16* Alds = (_Float16*)smem;            // 48 KB (XOR-swizzled x)
  _Float16* Sst = (_Float16*)(smem + 49152);   // 16 KB (512 rows x 16 h)
  int t = bid >> 3;
  bool is63 = (t == 63);
  int lane = tid & 63, og = tid >> 6;
  int l15 = lane & 15, q4 = lane >> 4, q0 = q4 * 8;

  {  // stage x -> Alds[m=b*3+c][k=n], swizzled, coalesced float4 reads
    int b = tid >> 5, li = tid & 31;
    const float4* xb = (const float4*)(p.x + (size_t)(b * 64 + t) * 1536);
#pragma unroll
    for (int k = 0; k < 12; ++k) {
      float4 v = xb[k * 32 + li];
      int j0 = (k * 32 + li) * 4;
#pragma unroll
      for (int e = 0; e < 4; ++e) {
        int j = j0 + e;
        int n = (j * 21846) >> 16;  // exact j/3 for j<2048
        int c = j - n * 3;
        int m = b * 3 + c;
        float val = (e == 0) ? v.x : (e == 1) ? v.y : (e == 2) ? v.z : v.w;
        Alds[m * 512 + ((((n >> 3) ^ (m & 7)) << 3) | (n & 7))] = (_Float16)val;
      }
    }
  }
  __syncthreads();

  int nt = og & 1, mat = og >> 1;
  const float4_t zero4 = {0.f, 0.f, 0.f, 0.f};
  for (int half = 0; half < 2; ++half) {
    int nc = (bid & 7) + half * 8;
    int n0g = nc * 32;
    float4_t acc[3];
    acc[0] = zero4; acc[1] = zero4; acc[2] = zero4;
    if (og < 6) {
      const _Float16* Bmat = (mat == 0) ? p.adjT : (mat == 1) ? p.AfT : p.AbT;
      int n = n0g + nt * 16 + l15;
      for (int kb = 0; kb < 16; ++kb) {
        half8_t b0 = *(const half8_t*)&Bmat[(size_t)n * 512 + kb * 32 + q0];
#pragma unroll
        for (int mt = 0; mt < 3; ++mt) {
          int m = mt * 16 + l15;
          half8_t a = *(const half8_t*)
              &Alds[m * 512 + ((((kb * 4 + q4) ^ (m & 7)) << 3))];
          acc[mt] = __builtin_amdgcn_mfma_f32_16x16x32_f16(a, b0, acc[mt], 0, 0, 0);
        }
      }
    } else {  // fill waves: x-copy + bias + zeros
      int lt = (og - 6) * 64 + lane;  // 0..127
      for (int i = lt; i < 512; i += 128) {
        int tb = i >> 5, nl = i & 31;
        int nn = n0g + nl;
        _Float16* row = &Sst[i * 16];
#pragma unroll
        for (int c = 0; c < 3; ++c) {
          int m = tb * 3 + c;
          row[c] = Alds[m * 512 + ((((nn >> 3) ^ (m & 7)) << 3) | (nn & 7))];
        }
        row[9] = (_Float16)1.f;
#pragma unroll
        for (int z = 10; z < 16; ++z) row[z] = (_Float16)0.f;
      }
    }
    // scatter MFMA results (C layout: col=l15, row=q4*4+r)
    if (og < 6 && mat < 2) {
#pragma unroll
      for (int mt = 0; mt < 3; ++mt)
#pragma unroll
        for (int r = 0; r < 4; ++r) {
          int m = mt * 16 + q4 * 4 + r;
          int tb = (m * 21846) >> 16;
          int c = m - tb * 3;
          Sst[(tb * 32 + nt * 16 + l15) * 16 + 3 + mat * 3 + c] = (_Float16)acc[mt][r];
        }
    }
    __syncthreads();
    for (int i = tid; i < 1024; i += 512) {
      int rrow = i >> 1, h = i & 1;
      int tb = rrow >> 5, nl = rrow & 31;
      ((uint4*)p.msg16)[(((size_t)(t * 16 + tb) * 512) + n0g + nl) * 2 + h] =
          ((const uint4*)Sst)[i];
    }
    if (is63) {
      __syncthreads();  // msg16 copy-out done before overwrite
      if (og < 6 && mat == 2) {
#pragma unroll
        for (int mt = 0; mt < 3; ++mt)
#pragma unroll
          for (int r = 0; r < 4; ++r) {
            int m = mt * 16 + q4 * 4 + r;
            int tb = (m * 21846) >> 16;
            int c = m - tb * 3;
            Sst[(tb * 32 + nt * 16 + l15) * 16 + 6 + c] = (_Float16)acc[mt][r];
          }
      }
      __syncthreads();
      for (int i = tid; i < 1024; i += 512) {
        int rrow = i >> 1, h = i & 1;
        int tb = rrow >> 5, nl = rrow & 31;
        ((uint4*)p.msgb16)[(((size_t)tb * 512) + n0g + nl) * 2 + h] =
            ((const uint4*)Sst)[i];
      }
    }
    __syncthreads();  // Sst free for next half
  }
}

// ---------------- phase 3: rec (R11 verbatim) -------------------------------
__device__ void phase_rec(const P& p, char* smem, int bid, int tid) {
  _Float16* Cbuf = (_Float16*)smem;             // 4 KB
  _Float16* Gbuf = (_Float16*)(smem + 4096);    // 4 KB
  float* hf_lds = (float*)(smem + 8192);        // 8 KB
  float* hb_lds = (float*)(smem + 16384);       // 8 KB
  float* hdec_lds = (float*)(smem + 24576);     // 768 B
  int b = bid >> 5;
  int nt = bid & 31;
  int n0 = nt * 16;
  int lane = tid & 63, og = tid >> 6;
  int l15 = lane & 15, q4 = lane >> 4;

  half8_t afrag[3][5];
#pragma unroll
  for (int gi = 0; gi < 3; ++gi)
#pragma unroll
    for (int kb = 0; kb < 5; ++kb) {
      afrag[gi][kb] = *(const half8_t*)
          &p.ufrag[(size_t)(((og * 3 + gi) * 5 + kb) * 512) + lane * 8];
      PIN(afrag[gi][kb]);
    }

  if (tid < 256) {
    uint4 z; z.x = z.y = z.z = z.w = 0;
    ((uint4*)Cbuf)[tid] = z;
  }
  float cr[4] = {0.f, 0.f, 0.f, 0.f};

  const float4_t zero4 = {0.f, 0.f, 0.f, 0.f};
  union H4U { fp16x2_t h2[2]; unsigned long long u; };
  const char* base = (const char*)p.msg16 +
                     ((size_t)(b * 512 + n0 + l15)) * 32 + (q4 & 1) * 16;
  const char* mrow = (q4 < 2) ? base : (const char*)p.zpad;
  size_t tstr = (q4 < 2) ? (size_t)16 * 512 * 32 : 0;
  half8_t bm = *(const half8_t*)mrow;  // t=0

  int kb_w = og >> 1;
  int lane_w = ((og & 1) * 2 + (q4 >> 1)) * 16 + l15;
  int j0 = (q4 & 1) * 4;
  __syncthreads();

  for (int t = 0; t < 64; ++t) {
    int tn = (t < 63) ? t + 1 : 63;
    half8_t bm_n = *(const half8_t*)(mrow + (size_t)tn * tstr);

    half8_t cf[4];
#pragma unroll
    for (int kb = 0; kb < 4; ++kb)
      cf[kb] = *(const half8_t*)&Cbuf[(kb * 64 + lane) * 8];

    float4_t accr = zero4, accu = zero4;
#pragma unroll
    for (int kb = 0; kb < 4; ++kb) {
      accr = __builtin_amdgcn_mfma_f32_16x16x32_f16(afrag[0][kb], cf[kb], accr, 0, 0, 0);
      accu = __builtin_amdgcn_mfma_f32_16x16x32_f16(afrag[1][kb], cf[kb], accu, 0, 0, 0);
    }
    accr = __builtin_amdgcn_mfma_f32_16x16x32_f16(afrag[0][4], bm, accr, 0, 0, 0);
    accu = __builtin_amdgcn_mfma_f32_16x16x32_f16(afrag[1][4], bm, accu, 0, 0, 0);
    float4_t accg_p = __builtin_amdgcn_mfma_f32_16x16x32_f16(afrag[2][4], bm, zero4, 0, 0, 0);

    float uu[4];
    {  // r = rcp(1+exp2(.)); rc -> Gbuf; u hoisted into pre-barrier gap
      H4U v;
#pragma unroll
      for (int r = 0; r < 2; ++r) {
        float a = rcp_(1.f + exp2_(accr[2 * r])) * cr[2 * r];
        float bq = rcp_(1.f + exp2_(accr[2 * r + 1])) * cr[2 * r + 1];
        v.h2[r] = __builtin_amdgcn_cvt_pkrtz(a, bq);
      }
      *(unsigned long long*)&Gbuf[(kb_w * 64 + lane_w) * 8 + j0] = v.u;
#pragma unroll
      for (int r = 0; r < 4; ++r) uu[r] = rcp_(1.f + exp2_(accu[r]));
    }
    __syncthreads();  // rc visible; Cbuf reads done

    half8_t gf[4];
#pragma unroll
    for (int kb = 0; kb < 4; ++kb)
      gf[kb] = *(const half8_t*)&Gbuf[(kb * 64 + lane) * 8];
    float4_t accg = accg_p;
#pragma unroll
    for (int kb = 0; kb < 4; ++kb)
      accg = __builtin_amdgcn_mfma_f32_16x16x32_f16(afrag[2][kb], gf[kb], accg, 0, 0, 0);

    {  // g = 1-2*rcp(1+exp2(.)); c update
      H4U v;
      float cn[4];
#pragma unroll
      for (int r = 0; r < 4; ++r) {
        float gg = fmaf(-2.f, rcp_(exp2_(accg[r]) + 1.f), 1.f);
        cn[r] = fmaf(uu[r], cr[r] - gg, gg);  // u*c + (1-u)*g
        cr[r] = cn[r];
      }
      v.h2[0] = __builtin_amdgcn_cvt_pkrtz(cn[0], cn[1]);
      v.h2[1] = __builtin_amdgcn_cvt_pkrtz(cn[2], cn[3]);
      *(unsigned long long*)&Cbuf[(kb_w * 64 + lane_w) * 8 + j0] = v.u;
    }
    __syncthreads();  // c_{t+1} visible; Gbuf reads done
    bm = bm_n;
  }

  // backward cell at t=63, c0=0: h_back = (1-sig(pre_u))*tanh(pre_g)
  {
    const char* bb_base = (const char*)p.msgb16 +
                          ((size_t)(b * 512 + n0 + l15)) * 32 + (q4 & 1) * 16;
    const char* bp = (q4 < 2) ? bb_base : (const char*)p.zpad;
    half8_t bbk = *(const half8_t*)bp;
    half8_t au_f = *(const half8_t*)&p.wbfrag[(size_t)((og * 2 + 0) * 512) + lane * 8];
    half8_t ag_f = *(const half8_t*)&p.wbfrag[(size_t)((og * 2 + 1) * 512) + lane * 8];
    float4_t au = __builtin_amdgcn_mfma_f32_16x16x32_f16(au_f, bbk, zero4, 0, 0, 0);
    float4_t ag = __builtin_amdgcn_mfma_f32_16x16x32_f16(ag_f, bbk, zero4, 0, 0, 0);
#pragma unroll
    for (int r = 0; r < 4; ++r) {
      int row = og * 16 + q4 * 4 + r;
      float uu2 = rcp_(1.f + exp2_(au[r]));
      float gg = fmaf(-2.f, rcp_(exp2_(ag[r]) + 1.f), 1.f);
      hb_lds[row * 16 + l15] = (1.f - uu2) * gg;
      hf_lds[row * 16 + l15] = cr[r];
    }
  }
  __syncthreads();

  if (tid < 192) {
    int i = tid >> 4, cc = tid & 15;
    const float* dwa = p.dec_w + (size_t)i * 512;
    const float* dwb = dwa + 256;
    float hd = p.dec_b[i];
    for (int e = 0; e < 128; ++e) {
      hd = fmaf(dwa[e] + dwb[e], hf_lds[e * 16 + cc], hd);
      hd = fmaf(dwa[128 + e] + dwb[128 + e], hb_lds[e * 16 + cc], hd);
    }
    hdec_lds[i * 16 + cc] = hd;
  }
  __syncthreads();
  if (tid < 192) {
    int o = tid >> 4, cc = tid & 15;
    float v = p.out_b[o];
#pragma unroll
    for (int i = 0; i < 12; ++i)
      v = fmaf(p.out_w[o * 12 + i], hdec_lds[i * 16 + cc], v);
    p.out[((size_t)(b * 12 + o)) * 512 + n0 + cc] = v;
  }
}

// ---------------- fused cooperative kernel + fallbacks ----------------------
__global__ __launch_bounds__(512, 4) void fused_kernel(P p) {
  __shared__ __align__(16) char smem[65536];
  cg::grid_group grid = cg::this_grid();
  phase_prep(p, smem, blockIdx.x, threadIdx.x);
  grid.sync();
  phase_msg(p, smem, blockIdx.x, threadIdx.x);
  grid.sync();
  phase_rec(p, smem, blockIdx.x, threadIdx.x);
}

__global__ __launch_bounds__(512, 4) void prep_k(P p) {
  __shared__ __align__(16) char smem[65536];
  phase_prep(p, smem, blockIdx.x, threadIdx.x);
}
__global__ __launch_bounds__(512, 4) void msg_k(P p) {
  __shared__ __align__(16) char smem[65536];
  phase_msg(p, smem, blockIdx.x, threadIdx.x);
}
__global__ __launch_bounds__(512, 4) void rec_k(P p) {
  __shared__ __align__(16) char smem[65536];
  phase_rec(p, smem, blockIdx.x, threadIdx.x);
}

extern "C" void kernel_launch(void* const* d_in, const int* in_sizes, int n_in,
                              void* d_out, int out_size, void* d_ws, size_t ws_size,
                              hipStream_t stream) {
  (void)in_sizes; (void)n_in; (void)out_size; (void)ws_size;
  _Float16* h = (_Float16*)d_ws;
  P p;
  p.E1f = (const float*)d_in[5];
  p.E2f = (const float*)d_in[6];
  p.E1b = (const float*)d_in[10];
  p.E2b = (const float*)d_in[11];
  p.adj = (const float*)d_in[1];
  p.x   = (const float*)d_in[0];
  p.Wf  = (const float*)d_in[2];
  p.Uf  = (const float*)d_in[3];
  p.bf  = (const float*)d_in[4];
  p.Wb  = (const float*)d_in[7];
  p.bb  = (const float*)d_in[9];
  p.dec_w = (const float*)d_in[12];
  p.dec_b = (const float*)d_in[13];
  p.out_w = (const float*)d_in[14];
  p.out_b = (const float*)d_in[15];
  p.out = (float*)d_out;
  p.adjT   = h;                // 262144
  p.AfT    = h + 262144;       // 262144
  p.AbT    = h + 524288;       // 262144
  p.ufrag  = h + 786432;       // 61440
  p.wbfrag = h + 847872;       // 8192
  p.zpad   = h + 856064;       // 64
  p.msg16  = h + 856128;       // 8388608 (32B rows)
  p.msgb16 = h + 9244736;      // 131072

  void* args[] = {&p};
  hipError_t err = hipLaunchCooperativeKernel((const void*)fused_kernel,
                                              dim3(512), dim3(512), args, 0, stream);
  if (err != hipSuccess) {
    (void)hipGetLastError();  // clear sticky error, use 3-launch fallback
    prep_k<<<512, 512, 0, stream>>>(p);
    msg_k<<<512, 512, 0, stream>>>(p);
    rec_k<<<512, 512, 0, stream>>>(p);
  }
}

// Round 13
// 211.007 us; speedup vs baseline: 1.6895x; 1.6895x over previous
//
#include <hip/hip_runtime.h>

// IBNModel: graph-coupled bidirectional GRU + decoder. All fp32 in/out.
// B=16, H=64, N=512, C=3, E=128, D=32, L_OUT=12, LAYERS=2.
//
// TWO launches (each boundary ~8 us — measured R8 vs R9/R10):
//  K1 prep  : softmax(relu(E1 E2^T)) -> fp16 transposed AfT/AbT; adj->adjT;
//             ufrag/wbfrag pre-scaled (-log2e r,u / +2log2e g); x -> xT16.
//  K2 fused : per-block PRIVATE msg prologue (block (b,nt) computes the msg
//             GEMM for its own 16 columns only -> no cross-block dependency,
//             no grid sync) + R8-proven MFMA recurrence loop + backward +
//             decoder. msg rows 24 B: [x(3),adj(3),Af(3),1,0,0] (R8 mux).

typedef _Float16 half8_t __attribute__((ext_vector_type(8)));
typedef __fp16 fp16x2_t __attribute__((ext_vector_type(2)));
typedef float float4_t __attribute__((ext_vector_type(4)));

#define PIN(x) asm volatile("" : "+v"(x))

__device__ __forceinline__ float exp2_(float x) { return __builtin_amdgcn_exp2f(x); }
__device__ __forceinline__ float rcp_(float x) { return __builtin_amdgcn_rcpf(x); }

// ---------------- K1: prep --------------------------------------------------
__global__ __launch_bounds__(256) void prep_kernel(
    const float* __restrict__ E1f, const float* __restrict__ E2f,
    const float* __restrict__ E1b, const float* __restrict__ E2b,
    const float* __restrict__ adj, const float* __restrict__ x,
    const float* __restrict__ Wf, const float* __restrict__ Uf,
    const float* __restrict__ bf, const float* __restrict__ Wb,
    const float* __restrict__ bb, _Float16* __restrict__ adjT,
    _Float16* __restrict__ AfT, _Float16* __restrict__ AbT,
    _Float16* __restrict__ ufrag, _Float16* __restrict__ wbfrag,
    _Float16* __restrict__ xT16) {
  int bid = blockIdx.x;
  int tid = threadIdx.x;
  if (bid >= 1288) {  // xT16: 1024 blocks, one per (b,t)
    int bid2 = bid - 1288;
    int b = bid2 >> 6, t = bid2 & 63;
    const float2* xp = (const float2*)(x + (size_t)(b * 64 + t) * 1536);
    float2 f0 = xp[tid * 3], f1 = xp[tid * 3 + 1], f2 = xp[tid * 3 + 2];
    _Float16* dst = xT16 + (size_t)(b * 64 + t) * 1536;
    int n0_ = tid * 2;
    dst[n0_] = (_Float16)f0.x;
    dst[512 + n0_] = (_Float16)f0.y;
    dst[1024 + n0_] = (_Float16)f1.x;
    dst[n0_ + 1] = (_Float16)f1.y;
    dst[512 + n0_ + 1] = (_Float16)f2.x;
    dst[1024 + n0_ + 1] = (_Float16)f2.y;
    return;
  }
  if (bid >= 1272) {  // wbfrag: 16 regions r2 = og*2 + (gi-1), pre-scaled
    int r2 = bid - 1272;
    int gi = 1 + (r2 & 1);
    int og = r2 >> 1;
    float scl = (gi == 2) ? 2.8853902f : -1.4426950f;
    for (int e = tid; e < 512; e += 256) {
      int lane = e >> 3, j = e & 7;
      int o = og * 16 + (lane & 15);
      int q = (lane >> 4) * 8 + j;
      float v = (q < 9) ? Wb[gi * 1152 + o * 9 + q]
                        : (q == 9 ? bb[gi * 128 + o] : 0.f);
      wbfrag[r2 * 512 + e] = (_Float16)(v * scl);
    }
    return;
  }
  if (bid >= 1152) {  // ufrag: 120 regions r = (og*3+gi)*5+kb, pre-scaled
    int r = bid - 1152;
    int kb = r % 5;
    int gi = (r / 5) % 3;
    int og = r / 15;
    float scl = (gi == 2) ? 2.8853902f : -1.4426950f;
    for (int e = tid; e < 512; e += 256) {
      int lane = e >> 3, j = e & 7;
      int o = og * 16 + (lane & 15);
      int q4 = lane >> 4;
      float v;
      if (kb < 4) {
        v = Uf[gi * 16384 + o * 128 + kb * 32 + q4 * 8 + j];
      } else {
        int q = q4 * 8 + j;
        v = (q < 9) ? Wf[gi * 1152 + o * 9 + q]
                    : (q == 9 ? bf[gi * 128 + o] : 0.f);
      }
      ufrag[r * 512 + e] = (_Float16)(v * scl);
    }
    return;
  }
  if (bid >= 1024) {  // adj -> adjT fp16 (transpose)
    int base = (bid - 1024) * 4;
    for (int r = 0; r < 4; ++r) {
      int row = base + r;
      float v0 = adj[row * 512 + tid];
      float v1 = adj[row * 512 + tid + 256];
      adjT[(size_t)tid * 512 + row] = (_Float16)v0;
      adjT[(size_t)(tid + 256) * 512 + row] = (_Float16)v1;
    }
    return;
  }
  int which = bid >> 9;
  int row = bid & 511;
  const float* E1 = which ? E1b : E1f;
  const float* E2 = which ? E2b : E2f;
  _Float16* A = which ? AbT : AfT;
  __shared__ float e1s[32];
  __shared__ float red[256];
  if (tid < 32) e1s[tid] = E1[row * 32 + tid];
  __syncthreads();
  float s[2];
#pragma unroll
  for (int h = 0; h < 2; ++h) {
    int m = tid + h * 256;
    const float4* e2 = (const float4*)(E2 + m * 32);
    float acc = 0.f;
#pragma unroll
    for (int d4 = 0; d4 < 8; ++d4) {
      float4 v = e2[d4];
      acc = fmaf(v.x, e1s[d4 * 4 + 0], acc);
      acc = fmaf(v.y, e1s[d4 * 4 + 1], acc);
      acc = fmaf(v.z, e1s[d4 * 4 + 2], acc);
      acc = fmaf(v.w, e1s[d4 * 4 + 3], acc);
    }
    s[h] = fmaxf(acc, 0.f);
  }
  red[tid] = fmaxf(s[0], s[1]);
  __syncthreads();
  for (int off = 128; off > 0; off >>= 1) {
    if (tid < off) red[tid] = fmaxf(red[tid], red[tid + off]);
    __syncthreads();
  }
  float mx = red[0];
  __syncthreads();
  float e0 = __expf(s[0] - mx), e1v = __expf(s[1] - mx);
  red[tid] = e0 + e1v;
  __syncthreads();
  for (int off = 128; off > 0; off >>= 1) {
    if (tid < off) red[tid] += red[tid + off];
    __syncthreads();
  }
  float inv = rcp_(red[0]);
  A[(size_t)tid * 512 + row] = (_Float16)(e0 * inv);
  A[(size_t)(tid + 256) * 512 + row] = (_Float16)(e1v * inv);
}

// ---------------- K2: fused msg-prologue + recurrence -----------------------
// grid 512 = b(16) x ntile(32, 16 cols); 512 thr = 8 waves, 2 blocks/CU.
// Prologue: wave og -> chunk=og>>1 (16 t's), mat=og&1 (adj/Af); M=48(t,c),
// N=16, K=512 MFMA GEMM from xT16 (A) and adjT/AfT (B); og7 also does Ab
// for t=63. Results + x/bias assembled in LDS Sst -> private global slice
// msgS[s][t][nl][12]. Then R8-proven loop (mux 24B rows).
__global__ __launch_bounds__(512, 4) void rec_kernel(
    const _Float16* __restrict__ xT16, const _Float16* __restrict__ adjT,
    const _Float16* __restrict__ AfT, const _Float16* __restrict__ AbT,
    _Float16* __restrict__ msgS, _Float16* __restrict__ msgbS,
    const _Float16* __restrict__ ufrag, const _Float16* __restrict__ wbfrag,
    const float* __restrict__ dec_w, const float* __restrict__ dec_b,
    const float* __restrict__ out_w, const float* __restrict__ out_b,
    float* __restrict__ out) {
  __shared__ __align__(16) _Float16 Sst[1024 * 12];  // 24 KB [t][nl][12]
  __shared__ __align__(16) _Float16 Sb[64];          // Ab products [nl][4]
  __shared__ __align__(16) _Float16 Cbuf[2048];      // 4 KB
  __shared__ __align__(16) _Float16 Gbuf[2048];      // 4 KB
  __shared__ float hf_lds[128 * 16];
  __shared__ float hb_lds[128 * 16];
  __shared__ float hdec_lds[12 * 16];
  int tid = threadIdx.x, bid = blockIdx.x;
  int b = bid >> 5;
  int nt = bid & 31;
  int n0 = nt * 16;
  size_t s = (size_t)bid;
  int lane = tid & 63, og = tid >> 6;
  int l15 = lane & 15, q4 = lane >> 4, q0 = q4 * 8;
  const float4_t zero4 = {0.f, 0.f, 0.f, 0.f};

  // ---- prologue: private msg GEMM for this block's 16 columns ----
  {
    int chunk = og >> 1, mat = og & 1;
    const _Float16* Bmat = mat ? AfT : adjT;
    int n = n0 + l15;
    float4_t acc[3];
    acc[0] = zero4; acc[1] = zero4; acc[2] = zero4;
    float4_t accb = zero4;
    for (int kb = 0; kb < 16; ++kb) {
      half8_t bfrg = *(const half8_t*)&Bmat[(size_t)n * 512 + kb * 32 + q0];
#pragma unroll
      for (int mt = 0; mt < 3; ++mt) {
        int m = mt * 16 + l15;
        int tl = (m * 21846) >> 16;  // m/3
        int c = m - tl * 3;
        int t = chunk * 16 + tl;
        half8_t a = *(const half8_t*)
            &xT16[((size_t)(b * 64 + t) * 3 + c) * 512 + kb * 32 + q0];
        acc[mt] = __builtin_amdgcn_mfma_f32_16x16x32_f16(a, bfrg, acc[mt], 0, 0, 0);
      }
      if (og == 7) {  // Ab tile (t=63 rows, m<3 used)
        half8_t b2 = *(const half8_t*)&AbT[(size_t)n * 512 + kb * 32 + q0];
        int c = l15 % 3;
        half8_t a = *(const half8_t*)
            &xT16[((size_t)(b * 64 + 63) * 3 + c) * 512 + kb * 32 + q0];
        accb = __builtin_amdgcn_mfma_f32_16x16x32_f16(a, b2, accb, 0, 0, 0);
      }
    }
    // fill x (j0-2), bias (j9), zeros (j10-11)
    for (int i = tid; i < 1024; i += 512) {
      int t = i >> 4, nl = i & 15;
      _Float16* row = &Sst[i * 12];
#pragma unroll
      for (int c = 0; c < 3; ++c)
        row[c] = xT16[((size_t)(b * 64 + t) * 3 + c) * 512 + n0 + nl];
      row[9] = (_Float16)1.f;
      row[10] = (_Float16)0.f;
      row[11] = (_Float16)0.f;
    }
    // scatter MFMA results (C layout: col=l15, row=q4*4+r)
#pragma unroll
    for (int mt = 0; mt < 3; ++mt)
#pragma unroll
      for (int r = 0; r < 4; ++r) {
        int m = mt * 16 + q4 * 4 + r;
        int tl = (m * 21846) >> 16;
        int c = m - tl * 3;
        int t = chunk * 16 + tl;
        Sst[(t * 16 + l15) * 12 + 3 + mat * 3 + c] = (_Float16)acc[mt][r];
      }
    if (og == 7 && q4 == 0) {
#pragma unroll
      for (int r = 0; r < 3; ++r) Sb[l15 * 4 + r] = (_Float16)accb[r];
    }
  }
  __syncthreads();
  // copy slice to private global region (3072 uint2 = 24 KB)
  {
    uint2* dst = (uint2*)msgS + s * 3072;
    const uint2* src = (const uint2*)Sst;
    for (int i = tid; i < 3072; i += 512) dst[i] = src[i];
  }
  if (tid < 16) {  // msgb row: msg63 with j6-8 = Ab product
    int nl = tid;
    _Float16* d = msgbS + s * 192 + nl * 12;
#pragma unroll
    for (int j = 0; j < 12; ++j)
      d[j] = (j >= 6 && j < 9) ? Sb[nl * 4 + (j - 6)]
                               : Sst[(63 * 16 + nl) * 12 + j];
  }

  // ---- persistent A frags (after prologue to ease reg pressure) ----
  half8_t afrag[3][5];
#pragma unroll
  for (int gi = 0; gi < 3; ++gi)
#pragma unroll
    for (int kb = 0; kb < 5; ++kb) {
      afrag[gi][kb] = *(const half8_t*)
          &ufrag[(size_t)(((og * 3 + gi) * 5 + kb) * 512) + lane * 8];
      PIN(afrag[gi][kb]);
    }
  if (tid < 256) {
    uint4 z; z.x = z.y = z.z = z.w = 0;
    ((uint4*)Cbuf)[tid] = z;
  }
  float cr[4] = {0.f, 0.f, 0.f, 0.f};

  union H4U { fp16x2_t h2[2]; unsigned long long u; };
  union U16 { uint4 u4; half8_t h8; };
  unsigned odd = q4 & 1;
  const char* mrow = (const char*)msgS + s * 24576 + l15 * 24;
  const size_t tstride = 384;  // 16 rows * 24 B per t

  int kb_w = og >> 1;
  int lane_w = ((og & 1) * 2 + (q4 >> 1)) * 16 + l15;
  int j0 = (q4 & 1) * 4;
  __syncthreads();  // slice visible (vmcnt(0) drained at barrier)

  // load bmsg for t=0
  U16 bu;
  {
    uint4 lo = *(const uint4*)mrow;
    uint2 hi = *(const uint2*)(mrow + 16);
    bu.u4.x = odd ? hi.x : lo.x;
    bu.u4.y = odd ? hi.y : lo.y;
    bu.u4.z = odd ? 0u : lo.z;
    bu.u4.w = odd ? 0u : lo.w;
  }
  half8_t bm = bu.h8;

  for (int t = 0; t < 64; ++t) {
    // prefetch next step's msg row
    int tn = (t < 63) ? t + 1 : 63;
    const char* p = mrow + (size_t)tn * tstride;
    uint4 lo = *(const uint4*)p;
    uint2 hi = *(const uint2*)(p + 16);

    half8_t cf[4];
#pragma unroll
    for (int kb = 0; kb < 4; ++kb)
      cf[kb] = *(const half8_t*)&Cbuf[(kb * 64 + lane) * 8];

    float4_t accr = zero4, accu = zero4;
#pragma unroll
    for (int kb = 0; kb < 4; ++kb) {
      accr = __builtin_amdgcn_mfma_f32_16x16x32_f16(afrag[0][kb], cf[kb], accr, 0, 0, 0);
      accu = __builtin_amdgcn_mfma_f32_16x16x32_f16(afrag[1][kb], cf[kb], accu, 0, 0, 0);
    }
    accr = __builtin_amdgcn_mfma_f32_16x16x32_f16(afrag[0][4], bm, accr, 0, 0, 0);
    accu = __builtin_amdgcn_mfma_f32_16x16x32_f16(afrag[1][4], bm, accu, 0, 0, 0);
    float4_t accg_p = __builtin_amdgcn_mfma_f32_16x16x32_f16(afrag[2][4], bm, zero4, 0, 0, 0);

    float uu[4];
    {  // r = rcp(1+exp2(.)) [pre-scaled -log2e]; rc -> Gbuf; u hoisted
      H4U v;
#pragma unroll
      for (int r = 0; r < 2; ++r) {
        float a = rcp_(1.f + exp2_(accr[2 * r])) * cr[2 * r];
        float bq = rcp_(1.f + exp2_(accr[2 * r + 1])) * cr[2 * r + 1];
        v.h2[r] = __builtin_amdgcn_cvt_pkrtz(a, bq);
      }
      *(unsigned long long*)&Gbuf[(kb_w * 64 + lane_w) * 8 + j0] = v.u;
#pragma unroll
      for (int r = 0; r < 4; ++r) uu[r] = rcp_(1.f + exp2_(accu[r]));
    }
    __syncthreads();  // rc visible; Cbuf reads done

    half8_t gf[4];
#pragma unroll
    for (int kb = 0; kb < 4; ++kb)
      gf[kb] = *(const half8_t*)&Gbuf[(kb * 64 + lane) * 8];
    float4_t accg = accg_p;
#pragma unroll
    for (int kb = 0; kb < 4; ++kb)
      accg = __builtin_amdgcn_mfma_f32_16x16x32_f16(afrag[2][kb], gf[kb], accg, 0, 0, 0);

    {  // g = 1-2*rcp(1+exp2(.)) [pre-scaled +2log2e]; c update
      H4U v;
      float cn[4];
#pragma unroll
      for (int r = 0; r < 4; ++r) {
        float gg = fmaf(-2.f, rcp_(exp2_(accg[r]) + 1.f), 1.f);
        cn[r] = fmaf(uu[r], cr[r] - gg, gg);  // u*c + (1-u)*g
        cr[r] = cn[r];
      }
      v.h2[0] = __builtin_amdgcn_cvt_pkrtz(cn[0], cn[1]);
      v.h2[1] = __builtin_amdgcn_cvt_pkrtz(cn[2], cn[3]);
      *(unsigned long long*)&Cbuf[(kb_w * 64 + lane_w) * 8 + j0] = v.u;
    }
    __syncthreads();  // c_{t+1} visible; Gbuf reads done

    bu.u4.x = odd ? hi.x : lo.x;
    bu.u4.y = odd ? hi.y : lo.y;
    bu.u4.z = odd ? 0u : lo.z;
    bu.u4.w = odd ? 0u : lo.w;
    bm = bu.h8;
  }

  // backward cell at t=63, c0=0: h_back = (1-sig(pre_u))*tanh(pre_g)
  {
    const char* bp = (const char*)msgbS + s * 384 + l15 * 24;
    uint4 lo = *(const uint4*)bp;
    uint2 hi = *(const uint2*)(bp + 16);
    U16 bb2;
    bb2.u4.x = odd ? hi.x : lo.x;
    bb2.u4.y = odd ? hi.y : lo.y;
    bb2.u4.z = odd ? 0u : lo.z;
    bb2.u4.w = odd ? 0u : lo.w;
    half8_t au_f = *(const half8_t*)&wbfrag[(size_t)((og * 2 + 0) * 512) + lane * 8];
    half8_t ag_f = *(const half8_t*)&wbfrag[(size_t)((og * 2 + 1) * 512) + lane * 8];
    float4_t au = __builtin_amdgcn_mfma_f32_16x16x32_f16(au_f, bb2.h8, zero4, 0, 0, 0);
    float4_t ag = __builtin_amdgcn_mfma_f32_16x16x32_f16(ag_f, bb2.h8, zero4, 0, 0, 0);
#pragma unroll
    for (int r = 0; r < 4; ++r) {
      int row = og * 16 + q4 * 4 + r;
      float uu2 = rcp_(1.f + exp2_(au[r]));
      float gg = fmaf(-2.f, rcp_(exp2_(ag[r]) + 1.f), 1.f);
      hb_lds[row * 16 + l15] = (1.f - uu2) * gg;
      hf_lds[row * 16 + l15] = cr[r];
    }
  }
  __syncthreads();

  // decoder
  if (tid < 192) {
    int i = tid >> 4, cc = tid & 15;
    const float* dwa = dec_w + (size_t)i * 512;
    const float* dwb = dwa + 256;
    float hd = dec_b[i];
    for (int e = 0; e < 128; ++e) {
      hd = fmaf(dwa[e] + dwb[e], hf_lds[e * 16 + cc], hd);
      hd = fmaf(dwa[128 + e] + dwb[128 + e], hb_lds[e * 16 + cc], hd);
    }
    hdec_lds[i * 16 + cc] = hd;
  }
  __syncthreads();
  if (tid < 192) {
    int o = tid >> 4, cc = tid & 15;
    float v = out_b[o];
#pragma unroll
    for (int i = 0; i < 12; ++i) v = fmaf(out_w[o * 12 + i], hdec_lds[i * 16 + cc], v);
    out[((size_t)(b * 12 + o)) * 512 + n0 + cc] = v;
  }
}

extern "C" void kernel_launch(void* const* d_in, const int* in_sizes, int n_in,
                              void* d_out, int out_size, void* d_ws, size_t ws_size,
                              hipStream_t stream) {
  (void)in_sizes; (void)n_in; (void)out_size; (void)ws_size;
  const float* x     = (const float*)d_in[0];
  const float* adj   = (const float*)d_in[1];
  const float* Wf    = (const float*)d_in[2];
  const float* Uf    = (const float*)d_in[3];
  const float* bf    = (const float*)d_in[4];
  const float* E1f   = (const float*)d_in[5];
  const float* E2f   = (const float*)d_in[6];
  const float* Wb    = (const float*)d_in[7];
  const float* bb    = (const float*)d_in[9];
  const float* E1b   = (const float*)d_in[10];
  const float* E2b   = (const float*)d_in[11];
  const float* dec_w = (const float*)d_in[12];
  const float* dec_b = (const float*)d_in[13];
  const float* out_w = (const float*)d_in[14];
  const float* out_b = (const float*)d_in[15];

  _Float16* h      = (_Float16*)d_ws;
  _Float16* adjT   = h;                        //   262144
  _Float16* AfT    = h + 262144;               //   262144
  _Float16* AbT    = h + 524288;               //   262144
  _Float16* ufrag  = h + 786432;               //    61440
  _Float16* wbfrag = h + 847872;               //     8192
  _Float16* xT16   = h + 856064;               //  1572864
  _Float16* msgS   = h + 2428928;              //  6291456 (per-slice 24B rows)
  _Float16* msgbS  = h + 8720384;              //    98304
  // total 8,818,688 halves = 17.64 MB (R4-proven size)

  prep_kernel<<<2312, 256, 0, stream>>>(E1f, E2f, E1b, E2b, adj, x, Wf, Uf, bf,
                                        Wb, bb, adjT, AfT, AbT, ufrag, wbfrag, xT16);
  rec_kernel<<<512, 512, 0, stream>>>(xT16, adjT, AfT, AbT, msgS, msgbS,
                                      ufrag, wbfrag, dec_w, dec_b, out_w, out_b,
                                      (float*)d_out);
}